// Round 1
// baseline (734.035 us; speedup 1.0000x reference)
//
#include <hip/hip_runtime.h>
#include <hip/hip_bf16.h>
#include <type_traits>

// ---- problem constants ----
#define B_    2
#define LQ_   21760
#define LEN_  21760
#define DM    256
#define NH    8
#define NL    4
#define NP    4
#define HD    32   // head dim

// workspace layout (bytes, all 256-aligned)
#define WS_VAL   0u                       // bf16 value: B*LEN*DM = 11,141,120 els * 2B
#define WS_OFF   22282240u                // f32 offsets raw: B*LQ*256 * 4B
#define WS_ATTN  66846720u                // f32 attn logits: B*LQ*128 * 4B
#define WS_SAMP  89129984u                // f32 sampled: B*LQ*256 * 4B  (end ~133.7MB)

__device__ __forceinline__ unsigned short f2bf(float v) {
    __hip_bfloat16 h = __float2bfloat16(v);
    return *reinterpret_cast<unsigned short*>(&h);
}

// ---------------------------------------------------------------------------
// Generic fp32 GEMM: C[M,N] = A[M,K] @ W[K,N] + bias[N]
// 64x64 tile, 16 k-slice, 256 threads, 4x4 micro-tile per thread.
// TOut = float or __hip_bfloat16.
// M % 64 == 0, N % 64 == 0, K % 16 == 0 (holds for all 4 uses).
// ---------------------------------------------------------------------------
template <typename TOut>
__global__ __launch_bounds__(256) void gemm64(const float* __restrict__ A,
                                              const float* __restrict__ Wm,
                                              const float* __restrict__ bias,
                                              TOut* __restrict__ C,
                                              int M, int N, int K) {
    __shared__ float As[16][68];  // [k][m], pad 68 -> 16B-aligned rows, 2-way max conflict
    __shared__ float Bs[16][64];  // [k][n]

    const int t  = threadIdx.x;
    const int tx = t & 15;        // n-dir
    const int ty = t >> 4;        // m-dir
    const int m0 = blockIdx.x * 64;
    const int n0 = blockIdx.y * 64;

    // staging indices
    const int am = t >> 2;          // 0..63 (row within A tile)
    const int ak = (t & 3) * 4;     // 0,4,8,12
    const int bk = t >> 4;          // 0..15 (row within W tile)
    const int bn = (t & 15) * 4;    // 0..60

    float acc[4][4] = {};

    for (int k0 = 0; k0 < K; k0 += 16) {
        float4 av = *(const float4*)&A[(size_t)(m0 + am) * K + (k0 + ak)];
        float4 bv = *(const float4*)&Wm[(size_t)(k0 + bk) * N + (n0 + bn)];
        As[ak + 0][am] = av.x;
        As[ak + 1][am] = av.y;
        As[ak + 2][am] = av.z;
        As[ak + 3][am] = av.w;
        *(float4*)&Bs[bk][bn] = bv;
        __syncthreads();

#pragma unroll
        for (int kk = 0; kk < 16; ++kk) {
            float4 a = *(const float4*)&As[kk][ty * 4];
            float4 b = *(const float4*)&Bs[kk][tx * 4];
            acc[0][0] += a.x * b.x; acc[0][1] += a.x * b.y; acc[0][2] += a.x * b.z; acc[0][3] += a.x * b.w;
            acc[1][0] += a.y * b.x; acc[1][1] += a.y * b.y; acc[1][2] += a.y * b.z; acc[1][3] += a.y * b.w;
            acc[2][0] += a.z * b.x; acc[2][1] += a.z * b.y; acc[2][2] += a.z * b.z; acc[2][3] += a.z * b.w;
            acc[3][0] += a.w * b.x; acc[3][1] += a.w * b.y; acc[3][2] += a.w * b.z; acc[3][3] += a.w * b.w;
        }
        __syncthreads();
    }

    const int n = n0 + tx * 4;
    float4 bb = *(const float4*)&bias[n];
#pragma unroll
    for (int i = 0; i < 4; ++i) {
        const int m = m0 + ty * 4 + i;
        float r0 = acc[i][0] + bb.x;
        float r1 = acc[i][1] + bb.y;
        float r2 = acc[i][2] + bb.z;
        float r3 = acc[i][3] + bb.w;
        if constexpr (std::is_same<TOut, float>::value) {
            float4 r = make_float4(r0, r1, r2, r3);
            *(float4*)&C[(size_t)m * N + n] = r;
        } else {
            ushort4 u;
            u.x = f2bf(r0); u.y = f2bf(r1); u.z = f2bf(r2); u.w = f2bf(r3);
            *(ushort4*)&C[(size_t)m * N + n] = u;  // 8B aligned (n%4==0)
        }
    }
}

// ---------------------------------------------------------------------------
// Deformable sampling: one block per (q, b); 256 threads = 8 heads x 32 dims.
// value: bf16 [B][LEN][256] (channel = h*32+d), offr: f32 [B][LQ][256],
// attnr: f32 [B][LQ][128], refp: f32 [B][LQ][4][2] -> samp f32 [B][LQ][256]
// ---------------------------------------------------------------------------
__global__ __launch_bounds__(256) void msda_sample(const __hip_bfloat16* __restrict__ value,
                                                   const float* __restrict__ offr,
                                                   const float* __restrict__ attnr,
                                                   const float* __restrict__ refp,
                                                   float* __restrict__ samp) {
    const int q = blockIdx.x;
    const int b = blockIdx.y;
    const int t = threadIdx.x;
    const int h = t >> 5;
    const int d = t & 31;
    const size_t bq = (size_t)b * LQ_ + q;

    __shared__ float s_off[256];
    __shared__ float s_attn[128];
    __shared__ float s_w[8][16];
    __shared__ float s_ref[8];

    s_off[t] = offr[bq * 256 + t];
    if (t < 128) s_attn[t] = attnr[bq * 128 + t];
    if (t < 8) s_ref[t] = refp[bq * 8 + t];
    __syncthreads();

    if (t < 8) {  // per-head softmax over 16 logits
        float m = -1e30f;
#pragma unroll
        for (int i = 0; i < 16; ++i) m = fmaxf(m, s_attn[t * 16 + i]);
        float e[16];
        float ssum = 0.f;
#pragma unroll
        for (int i = 0; i < 16; ++i) { e[i] = __expf(s_attn[t * 16 + i] - m); ssum += e[i]; }
        const float inv = 1.f / ssum;
#pragma unroll
        for (int i = 0; i < 16; ++i) s_w[t][i] = e[i] * inv;
    }
    __syncthreads();

    const __hip_bfloat16* vbase = value + (size_t)b * LEN_ * DM + h * HD + d;

    const int   Wls[4]    = {128, 64, 32, 16};
    const int   Hls[4]    = {128, 64, 32, 16};
    const int   starts[4] = {0, 16384, 20480, 21504};

    float acc = 0.f;
#pragma unroll
    for (int l = 0; l < NL; ++l) {
        const int Wl = Wls[l], Hl = Hls[l], st = starts[l];
        const float bx = s_ref[l * 2 + 0] * (float)Wl - 0.5f;
        const float by = s_ref[l * 2 + 1] * (float)Hl - 0.5f;
#pragma unroll
        for (int p = 0; p < NP; ++p) {
            const int oi = ((h * NL + l) * NP + p) * 2;
            const float ix = bx + s_off[oi];      // = loc_x * W - 0.5 (normalizer cancels)
            const float iy = by + s_off[oi + 1];
            const float fix = floorf(ix), fiy = floorf(iy);
            const int x0 = (int)fix, y0 = (int)fiy;
            const int x1 = x0 + 1,  y1 = y0 + 1;
            const float fx = ix - fix, fy = iy - fiy;

            const bool vx0 = (x0 >= 0) && (x0 < Wl);
            const bool vx1 = (x1 >= 0) && (x1 < Wl);
            const bool vy0 = (y0 >= 0) && (y0 < Hl);
            const bool vy1 = (y1 >= 0) && (y1 < Hl);
            const int cx0 = min(max(x0, 0), Wl - 1);
            const int cx1 = min(max(x1, 0), Wl - 1);
            const int cy0 = min(max(y0, 0), Hl - 1);
            const int cy1 = min(max(y1, 0), Hl - 1);

            // unconditional clamped loads (safe), masked by validity weights
            const float v00 = __bfloat162float(vbase[(size_t)(st + cy0 * Wl + cx0) * DM]);
            const float v01 = __bfloat162float(vbase[(size_t)(st + cy0 * Wl + cx1) * DM]);
            const float v10 = __bfloat162float(vbase[(size_t)(st + cy1 * Wl + cx0) * DM]);
            const float v11 = __bfloat162float(vbase[(size_t)(st + cy1 * Wl + cx1) * DM]);

            const float w00 = (1.f - fx) * (1.f - fy) * (float)(vx0 && vy0);
            const float w01 = fx * (1.f - fy)         * (float)(vx1 && vy0);
            const float w10 = (1.f - fx) * fy         * (float)(vx0 && vy1);
            const float w11 = fx * fy                 * (float)(vx1 && vy1);

            const float s = w00 * v00 + w01 * v01 + w10 * v10 + w11 * v11;
            acc += s_w[h][l * NP + p] * s;
        }
    }
    samp[bq * 256 + t] = acc;
}

extern "C" void kernel_launch(void* const* d_in, const int* in_sizes, int n_in,
                              void* d_out, int out_size, void* d_ws, size_t ws_size,
                              hipStream_t stream) {
    const float* query  = (const float*)d_in[0];
    const float* refp   = (const float*)d_in[1];
    const float* inpf   = (const float*)d_in[2];
    const float* W_off  = (const float*)d_in[3];
    const float* b_off  = (const float*)d_in[4];
    const float* W_attn = (const float*)d_in[5];
    const float* b_attn = (const float*)d_in[6];
    const float* W_val  = (const float*)d_in[7];
    const float* b_val  = (const float*)d_in[8];
    const float* W_out  = (const float*)d_in[9];
    const float* b_out  = (const float*)d_in[10];
    float* out = (float*)d_out;

    char* ws = (char*)d_ws;
    __hip_bfloat16* val_bf = (__hip_bfloat16*)(ws + WS_VAL);
    float* offr  = (float*)(ws + WS_OFF);
    float* attnr = (float*)(ws + WS_ATTN);
    float* sampd = (float*)(ws + WS_SAMP);

    const int M = B_ * LQ_;  // 43520 (also B_*LEN_)
    dim3 blk(256);

    // value = input_flatten @ W_val + b_val  -> bf16 ws
    gemm64<__hip_bfloat16><<<dim3(M / 64, DM / 64), blk, 0, stream>>>(inpf, W_val, b_val, val_bf, M, DM, DM);
    // offsets raw = query @ W_off + b_off
    gemm64<float><<<dim3(M / 64, DM / 64), blk, 0, stream>>>(query, W_off, b_off, offr, M, DM, DM);
    // attn logits = query @ W_attn + b_attn
    gemm64<float><<<dim3(M / 64, 128 / 64), blk, 0, stream>>>(query, W_attn, b_attn, attnr, M, 128, DM);
    // deformable sampling
    msda_sample<<<dim3(LQ_, B_), blk, 0, stream>>>(val_bf, offr, attnr, refp, sampd);
    // out = sampled @ W_out + b_out
    gemm64<float><<<dim3(M / 64, DM / 64), blk, 0, stream>>>(sampd, W_out, b_out, out, M, DM, DM);
}

// Round 2
// 333.120 us; speedup vs baseline: 2.2035x; 2.2035x over previous
//
#include <hip/hip_runtime.h>
#include <hip/hip_bf16.h>
#include <type_traits>

// ---- problem constants ----
#define B_    2
#define LQ_   21760
#define LEN_  21760
#define DM    256
#define NH    8
#define NL    4
#define NP    4
#define HD    32

// workspace layout (bytes)
#define WS_VAL   0u            // bf16 value [B*LEN][256]            22,282,240
#define WS_QBF   22282240u     // bf16 query [B*LQ][256]             22,282,240
#define WS_INBF  44564480u     // bf16 input_flatten; REUSED as samp 22,282,240
#define WS_OFF   66846720u     // f32 offsets [B*LQ][256]            44,564,480
#define WS_ATTN  111411200u    // f32 attn logits [B*LQ][128]        22,282,240
#define WS_WT    133693440u    // bf16 W^T: val(128K) off(128K) attn(64K) out(128K)

__device__ __forceinline__ unsigned short f2bf(float v) {
    __hip_bfloat16 h = __float2bfloat16(v);
    return *reinterpret_cast<unsigned short*>(&h);
}
__device__ __forceinline__ unsigned int pk2bf(float a, float b) {
    return (unsigned int)f2bf(a) | ((unsigned int)f2bf(b) << 16);
}

// ---------------------------------------------------------------------------
// f32 -> bf16 elementwise (vectorized x4)
// ---------------------------------------------------------------------------
__global__ __launch_bounds__(256) void cvt_bf16(const float* __restrict__ x,
                                                unsigned short* __restrict__ y, int n4) {
    int i = blockIdx.x * 256 + threadIdx.x;
    if (i < n4) {
        float4 v = ((const float4*)x)[i];
        ushort4 u;
        u.x = f2bf(v.x); u.y = f2bf(v.y); u.z = f2bf(v.z); u.w = f2bf(v.w);
        ((ushort4*)y)[i] = u;
    }
}

// ---------------------------------------------------------------------------
// W[K,N] f32 -> Wt[N,K] bf16 (16x16 LDS transpose)
// ---------------------------------------------------------------------------
__global__ __launch_bounds__(256) void wt_cvt(const float* __restrict__ W,
                                              unsigned short* __restrict__ Wt,
                                              int K, int N) {
    __shared__ float tile[16][17];
    const int n0 = blockIdx.x * 16, k0 = blockIdx.y * 16;
    const int tx = threadIdx.x & 15, ty = threadIdx.x >> 4;
    tile[ty][tx] = W[(size_t)(k0 + ty) * N + n0 + tx];
    __syncthreads();
    Wt[(size_t)(n0 + ty) * K + k0 + tx] = f2bf(tile[tx][ty]);
}

// ---------------------------------------------------------------------------
// MFMA bf16 GEMM: C[M,N] = A[M,K] @ Wt[N,K]^T + bias  (m97-style structure)
// 128x128 tile, BK=32, 256 threads = 4 waves, each wave 64x64 (4x4 MFMA tiles)
// M%128==0, N%128==0, K%32==0.
// ---------------------------------------------------------------------------
typedef __attribute__((ext_vector_type(8))) short bf16x8;
typedef __attribute__((ext_vector_type(4))) float f32x4;

template <typename TOut>
__global__ __launch_bounds__(256) void gemm_mfma(const unsigned short* __restrict__ A,
                                                 const unsigned short* __restrict__ Bt,
                                                 const float* __restrict__ bias,
                                                 TOut* __restrict__ C,
                                                 int M, int N, int K) {
    __shared__ unsigned short As[128 * 32];  // [m][k] row-major, 64B rows
    __shared__ unsigned short Bs[128 * 32];  // [n][k]
    const int t = threadIdx.x;
    const int wv = t >> 6;
    const int ln = t & 63;
    const int m0 = blockIdx.x * 128;
    const int n0 = blockIdx.y * 128;
    const int wm = (wv & 1) * 64;
    const int wn = (wv >> 1) * 64;
    const int lrow = ln & 15;
    const int kq = ln >> 4;  // 0..3

    f32x4 acc[4][4] = {};

    for (int k0 = 0; k0 < K; k0 += 32) {
#pragma unroll
        for (int c = 0; c < 2; ++c) {
            const int o = c * 4096 + wv * 1024 + ln * 16;  // byte offset in 8KB tile
            const int row = o >> 6;
            const int ke = (o & 63) >> 1;
            const unsigned short* ga = A + (size_t)(m0 + row) * K + k0 + ke;
            const unsigned short* gb = Bt + (size_t)(n0 + row) * K + k0 + ke;
            __builtin_amdgcn_global_load_lds(
                (const __attribute__((address_space(1))) void*)ga,
                (__attribute__((address_space(3))) void*)((char*)As + o), 16, 0, 0);
            __builtin_amdgcn_global_load_lds(
                (const __attribute__((address_space(1))) void*)gb,
                (__attribute__((address_space(3))) void*)((char*)Bs + o), 16, 0, 0);
        }
        __syncthreads();  // drains vmcnt (compiler emits full waitcnt before barrier)

        bf16x8 af[4], bfr[4];
#pragma unroll
        for (int i = 0; i < 4; ++i) {
            af[i]  = *(const bf16x8*)((char*)As + (wm + i * 16 + lrow) * 64 + kq * 16);
            bfr[i] = *(const bf16x8*)((char*)Bs + (wn + i * 16 + lrow) * 64 + kq * 16);
        }
#pragma unroll
        for (int i = 0; i < 4; ++i)
#pragma unroll
            for (int j = 0; j < 4; ++j)
                acc[i][j] = __builtin_amdgcn_mfma_f32_16x16x32_bf16(af[i], bfr[j], acc[i][j], 0, 0, 0);
        __syncthreads();
    }

    // epilogue: C/D mapping col = lane&15, row = (lane>>4)*4 + reg
#pragma unroll
    for (int j = 0; j < 4; ++j) {
        const int n = n0 + wn + j * 16 + lrow;
        const float bb = bias[n];
#pragma unroll
        for (int i = 0; i < 4; ++i) {
            const int mrow = m0 + wm + i * 16 + kq * 4;
#pragma unroll
            for (int r = 0; r < 4; ++r) {
                const float v = acc[i][j][r] + bb;
                if constexpr (std::is_same<TOut, float>::value) {
                    C[(size_t)(mrow + r) * N + n] = v;
                } else {
                    C[(size_t)(mrow + r) * N + n] = f2bf(v);
                }
            }
        }
    }
}

// ---------------------------------------------------------------------------
// Deformable sampling v2: block = 8 queries x 32 workers.
// Phase A: softmax + per-sample {4 clamped indices, 4 folded weights} -> LDS.
// Phase B: worker (h, dgroup of 8 ch) gathers uint4 (8 bf16) per corner.
// ---------------------------------------------------------------------------
#define QB 8
__global__ __launch_bounds__(256) void msda_sample2(const unsigned short* __restrict__ value,
                                                    const float* __restrict__ offr,
                                                    const float* __restrict__ attnr,
                                                    const float* __restrict__ refp,
                                                    unsigned short* __restrict__ samp) {
    __shared__ float s_off[QB * 256];       // 8 KB
    __shared__ float s_logit[QB * 128];     // 4 KB
    __shared__ float s_ref[QB * 8];         // 256 B
    __shared__ float s_aw[QB * 8 * 16];     // 4 KB
    __shared__ unsigned int s_pk[QB * 128 * 8];  // 32 KB: {i00,i01,i10,i11,w00,w01,w10,w11}

    const int t = threadIdx.x;
    const int bq0 = blockIdx.x * QB;
    const int b = bq0 / LQ_;  // LQ_ % QB == 0 -> uniform per block

    // phase 0: stage per-query data
    {
        const float4* so = (const float4*)(offr + (size_t)bq0 * 256);
        float4* dof = (float4*)s_off;
        dof[t] = so[t];
        dof[t + 256] = so[t + 256];
        ((float4*)s_logit)[t] = ((const float4*)(attnr + (size_t)bq0 * 128))[t];
        if (t < 16) ((float4*)s_ref)[t] = ((const float4*)(refp + (size_t)bq0 * 8))[t];
    }
    __syncthreads();

    // phase A1: 64 softmaxes (q,h) over 16 logits
    if (t < 64) {
        const float* lg = s_logit + (t >> 3) * 128 + (t & 7) * 16;
        float m = -1e30f;
#pragma unroll
        for (int i = 0; i < 16; ++i) m = fmaxf(m, lg[i]);
        float e[16], s = 0.f;
#pragma unroll
        for (int i = 0; i < 16; ++i) { e[i] = __expf(lg[i] - m); s += e[i]; }
        const float inv = 1.f / s;
#pragma unroll
        for (int i = 0; i < 16; ++i) s_aw[t * 16 + i] = e[i] * inv;
    }
    __syncthreads();

    // phase A2: 1024 samples, 4 per thread: indices + folded weights
    {
        const int Wls[4] = {128, 64, 32, 16};
        const int Hls[4] = {128, 64, 32, 16};
        const int st_[4] = {0, 16384, 20480, 21504};
#pragma unroll
        for (int ii = 0; ii < 4; ++ii) {
            const int s = t * 4 + ii;
            const int q = s >> 7;
            const int rest = s & 127;        // h*16 + l*4 + p
            const int h = rest >> 4;
            const int l = (rest >> 2) & 3;
            const int Wl = Wls[l], Hl = Hls[l], base = st_[l];
            const float ix = s_ref[q * 8 + l * 2]     * (float)Wl - 0.5f + s_off[q * 256 + rest * 2];
            const float iy = s_ref[q * 8 + l * 2 + 1] * (float)Hl - 0.5f + s_off[q * 256 + rest * 2 + 1];
            const float fix = floorf(ix), fiy = floorf(iy);
            const int x0 = (int)fix, y0 = (int)fiy;
            const int x1 = x0 + 1, y1 = y0 + 1;
            const float fx = ix - fix, fy = iy - fiy;
            const bool vx0 = (x0 >= 0) & (x0 < Wl);
            const bool vx1 = (x1 >= 0) & (x1 < Wl);
            const bool vy0 = (y0 >= 0) & (y0 < Hl);
            const bool vy1 = (y1 >= 0) & (y1 < Hl);
            const int cx0 = min(max(x0, 0), Wl - 1);
            const int cx1 = min(max(x1, 0), Wl - 1);
            const int cy0 = min(max(y0, 0), Hl - 1);
            const int cy1 = min(max(y1, 0), Hl - 1);
            const float aw = s_aw[(q * 8 + h) * 16 + (rest & 15)];
            const float w00 = aw * (1.f - fx) * (1.f - fy) * (float)(vx0 && vy0);
            const float w01 = aw * fx * (1.f - fy)         * (float)(vx1 && vy0);
            const float w10 = aw * (1.f - fx) * fy         * (float)(vx0 && vy1);
            const float w11 = aw * fx * fy                 * (float)(vx1 && vy1);
            // XOR-swizzle: bank bits 3-4 get h&3 -> 16-way conflict becomes 4-way
            const int slot = (s * 8) ^ ((h & 3) << 3);
            s_pk[slot + 0] = base + cy0 * Wl + cx0;
            s_pk[slot + 1] = base + cy0 * Wl + cx1;
            s_pk[slot + 2] = base + cy1 * Wl + cx0;
            s_pk[slot + 3] = base + cy1 * Wl + cx1;
            s_pk[slot + 4] = __float_as_uint(w00);
            s_pk[slot + 5] = __float_as_uint(w01);
            s_pk[slot + 6] = __float_as_uint(w10);
            s_pk[slot + 7] = __float_as_uint(w11);
        }
    }
    __syncthreads();

    // phase B: gather + accumulate. worker = (h, dg), 8 channels each
    const int q = t >> 5;
    const int w = t & 31;
    const int h = w >> 2;
    const int dg = w & 3;
    const unsigned short* vbase = value + (size_t)b * LEN_ * DM + h * HD + dg * 8;

    float acc[8] = {0.f, 0.f, 0.f, 0.f, 0.f, 0.f, 0.f, 0.f};
    const int sbase = q * 128 + h * 16;
#pragma unroll
    for (int lp = 0; lp < 16; ++lp) {
        const int s = sbase + lp;
        const int slot = (s * 8) ^ ((h & 3) << 3);
        const uint4 iv = *(const uint4*)&s_pk[slot];
        const uint4 wv = *(const uint4*)&s_pk[slot + 4];
        const uint4 v00 = *(const uint4*)(vbase + (size_t)iv.x * DM);
        const uint4 v01 = *(const uint4*)(vbase + (size_t)iv.y * DM);
        const uint4 v10 = *(const uint4*)(vbase + (size_t)iv.z * DM);
        const uint4 v11 = *(const uint4*)(vbase + (size_t)iv.w * DM);
#pragma unroll
        for (int c = 0; c < 4; ++c) {
            const unsigned int u00 = (&v00.x)[c], u01 = (&v01.x)[c];
            const unsigned int u10 = (&v10.x)[c], u11 = (&v11.x)[c];
            const float w00 = __uint_as_float(wv.x), w01 = __uint_as_float(wv.y);
            const float w10 = __uint_as_float(wv.z), w11 = __uint_as_float(wv.w);
            float a0 = acc[c * 2], a1 = acc[c * 2 + 1];
            a0 = fmaf(w00, __uint_as_float(u00 << 16), a0);
            a1 = fmaf(w00, __uint_as_float(u00 & 0xffff0000u), a1);
            a0 = fmaf(w01, __uint_as_float(u01 << 16), a0);
            a1 = fmaf(w01, __uint_as_float(u01 & 0xffff0000u), a1);
            a0 = fmaf(w10, __uint_as_float(u10 << 16), a0);
            a1 = fmaf(w10, __uint_as_float(u10 & 0xffff0000u), a1);
            a0 = fmaf(w11, __uint_as_float(u11 << 16), a0);
            a1 = fmaf(w11, __uint_as_float(u11 & 0xffff0000u), a1);
            acc[c * 2] = a0;
            acc[c * 2 + 1] = a1;
        }
    }
    uint4 o;
    o.x = pk2bf(acc[0], acc[1]);
    o.y = pk2bf(acc[2], acc[3]);
    o.z = pk2bf(acc[4], acc[5]);
    o.w = pk2bf(acc[6], acc[7]);
    *(uint4*)(samp + (size_t)(bq0 + q) * 256 + h * HD + dg * 8) = o;
}

extern "C" void kernel_launch(void* const* d_in, const int* in_sizes, int n_in,
                              void* d_out, int out_size, void* d_ws, size_t ws_size,
                              hipStream_t stream) {
    const float* query  = (const float*)d_in[0];
    const float* refp   = (const float*)d_in[1];
    const float* inpf   = (const float*)d_in[2];
    const float* W_off  = (const float*)d_in[3];
    const float* b_off  = (const float*)d_in[4];
    const float* W_attn = (const float*)d_in[5];
    const float* b_attn = (const float*)d_in[6];
    const float* W_val  = (const float*)d_in[7];
    const float* b_val  = (const float*)d_in[8];
    const float* W_out  = (const float*)d_in[9];
    const float* b_out  = (const float*)d_in[10];
    float* out = (float*)d_out;

    char* ws = (char*)d_ws;
    unsigned short* val_bf  = (unsigned short*)(ws + WS_VAL);
    unsigned short* q_bf    = (unsigned short*)(ws + WS_QBF);
    unsigned short* in_bf   = (unsigned short*)(ws + WS_INBF);
    unsigned short* samp_bf = (unsigned short*)(ws + WS_INBF);  // reuse after value GEMM
    float* offr  = (float*)(ws + WS_OFF);
    float* attnr = (float*)(ws + WS_ATTN);
    unsigned short* Wt_val  = (unsigned short*)(ws + WS_WT);
    unsigned short* Wt_off  = (unsigned short*)(ws + WS_WT + 131072);
    unsigned short* Wt_attn = (unsigned short*)(ws + WS_WT + 262144);
    unsigned short* Wt_out  = (unsigned short*)(ws + WS_WT + 327680);

    const int M = B_ * LQ_;          // 43520
    const int n4 = M * DM / 4;       // 2,785,280

    // converts + weight transposes
    cvt_bf16<<<dim3((n4 + 255) / 256), 256, 0, stream>>>(inpf, in_bf, n4);
    cvt_bf16<<<dim3((n4 + 255) / 256), 256, 0, stream>>>(query, q_bf, n4);
    wt_cvt<<<dim3(256 / 16, 256 / 16), 256, 0, stream>>>(W_val,  Wt_val,  256, 256);
    wt_cvt<<<dim3(256 / 16, 256 / 16), 256, 0, stream>>>(W_off,  Wt_off,  256, 256);
    wt_cvt<<<dim3(128 / 16, 256 / 16), 256, 0, stream>>>(W_attn, Wt_attn, 256, 128);
    wt_cvt<<<dim3(256 / 16, 256 / 16), 256, 0, stream>>>(W_out,  Wt_out,  256, 256);

    // GEMMs (MFMA bf16)
    gemm_mfma<unsigned short><<<dim3(M / 128, 2), 256, 0, stream>>>(in_bf, Wt_val, b_val, val_bf, M, 256, 256);
    gemm_mfma<float><<<dim3(M / 128, 2), 256, 0, stream>>>(q_bf, Wt_off, b_off, offr, M, 256, 256);
    gemm_mfma<float><<<dim3(M / 128, 1), 256, 0, stream>>>(q_bf, Wt_attn, b_attn, attnr, M, 128, 256);

    // sampling
    msda_sample2<<<dim3(M / QB), 256, 0, stream>>>(val_bf, offr, attnr, refp, samp_bf);

    // output projection
    gemm_mfma<float><<<dim3(M / 128, 2), 256, 0, stream>>>(samp_bf, Wt_out, b_out, out, M, 256, 256);
}

// Round 3
// 328.096 us; speedup vs baseline: 2.2373x; 1.0153x over previous
//
#include <hip/hip_runtime.h>
#include <hip/hip_bf16.h>
#include <type_traits>

// ---- problem constants ----
#define B_    2
#define LQ_   21760
#define LEN_  21760
#define DM    256
#define NH    8
#define NL    4
#define NP    4
#define HD    32

// workspace layout (bytes)
#define WS_VAL   0u            // bf16 value [B*LEN][256]            22,282,240
#define WS_QBF   22282240u     // bf16 query [B*LQ][256]             22,282,240
#define WS_INBF  44564480u     // bf16 input_flatten; REUSED as samp 22,282,240
#define WS_OA    66846720u     // f32 off|attn [B*LQ][384]           66,846,720
#define WS_WT    133693440u    // bf16 W^T: val(128K) oa(192K) out(128K)

typedef __attribute__((ext_vector_type(4))) float f32x4;
typedef __attribute__((ext_vector_type(8))) short bf16x8;
typedef __attribute__((ext_vector_type(4))) unsigned int u32x4;

__device__ __forceinline__ unsigned short f2bf(float v) {
    __hip_bfloat16 h = __float2bfloat16(v);
    return *reinterpret_cast<unsigned short*>(&h);
}
__device__ __forceinline__ unsigned int pk2bf(float a, float b) {
    return (unsigned int)f2bf(a) | ((unsigned int)f2bf(b) << 16);
}

// ---------------------------------------------------------------------------
// f32 -> bf16 elementwise (vectorized x4, nontemporal read)
// ---------------------------------------------------------------------------
__global__ __launch_bounds__(256) void cvt_bf16(const float* __restrict__ x,
                                                unsigned short* __restrict__ y, int n4) {
    int i = blockIdx.x * 256 + threadIdx.x;
    if (i < n4) {
        f32x4 v = __builtin_nontemporal_load((const f32x4*)x + i);
        ushort4 u;
        u.x = f2bf(v.x); u.y = f2bf(v.y); u.z = f2bf(v.z); u.w = f2bf(v.w);
        ((ushort4*)y)[i] = u;
    }
}

// ---------------------------------------------------------------------------
// W[K,N] f32 -> Wt[N,K] bf16 (16x16 LDS transpose)
// ---------------------------------------------------------------------------
__global__ __launch_bounds__(256) void wt_cvt(const float* __restrict__ W,
                                              unsigned short* __restrict__ Wt,
                                              int K, int N) {
    __shared__ float tile[16][17];
    const int n0 = blockIdx.x * 16, k0 = blockIdx.y * 16;
    const int tx = threadIdx.x & 15, ty = threadIdx.x >> 4;
    tile[ty][tx] = W[(size_t)(k0 + ty) * N + n0 + tx];
    __syncthreads();
    Wt[(size_t)(n0 + ty) * K + k0 + tx] = f2bf(tile[tx][ty]);
}

// ---------------------------------------------------------------------------
// MFMA bf16 GEMM: C[M,N] = A[M,K] @ Wt[N,K]^T + bias  (m97-style structure)
// 128x128 tile, BK=32, 256 threads = 4 waves. bias split: n<nsplit -> bias[n],
// else bias2[n-nsplit].
// ---------------------------------------------------------------------------
template <typename TOut>
__global__ __launch_bounds__(256) void gemm_mfma(const unsigned short* __restrict__ A,
                                                 const unsigned short* __restrict__ Bt,
                                                 const float* __restrict__ bias,
                                                 const float* __restrict__ bias2,
                                                 int nsplit,
                                                 TOut* __restrict__ C,
                                                 int M, int N, int K) {
    __shared__ unsigned short As[128 * 32];  // [m][k], 64B rows
    __shared__ unsigned short Bs[128 * 32];  // [n][k]
    const int t = threadIdx.x;
    const int wv = t >> 6;
    const int ln = t & 63;
    const int m0 = blockIdx.x * 128;
    const int n0 = blockIdx.y * 128;
    const int wm = (wv & 1) * 64;
    const int wn = (wv >> 1) * 64;
    const int lrow = ln & 15;
    const int kq = ln >> 4;

    f32x4 acc[4][4] = {};

    for (int k0 = 0; k0 < K; k0 += 32) {
#pragma unroll
        for (int c = 0; c < 2; ++c) {
            const int o = c * 4096 + wv * 1024 + ln * 16;
            const int row = o >> 6;
            const int ke = (o & 63) >> 1;
            const unsigned short* ga = A + (size_t)(m0 + row) * K + k0 + ke;
            const unsigned short* gb = Bt + (size_t)(n0 + row) * K + k0 + ke;
            __builtin_amdgcn_global_load_lds(
                (const __attribute__((address_space(1))) void*)ga,
                (__attribute__((address_space(3))) void*)((char*)As + o), 16, 0, 0);
            __builtin_amdgcn_global_load_lds(
                (const __attribute__((address_space(1))) void*)gb,
                (__attribute__((address_space(3))) void*)((char*)Bs + o), 16, 0, 0);
        }
        __syncthreads();

        bf16x8 af[4], bfr[4];
#pragma unroll
        for (int i = 0; i < 4; ++i) {
            af[i]  = *(const bf16x8*)((char*)As + (wm + i * 16 + lrow) * 64 + kq * 16);
            bfr[i] = *(const bf16x8*)((char*)Bs + (wn + i * 16 + lrow) * 64 + kq * 16);
        }
#pragma unroll
        for (int i = 0; i < 4; ++i)
#pragma unroll
            for (int j = 0; j < 4; ++j)
                acc[i][j] = __builtin_amdgcn_mfma_f32_16x16x32_bf16(af[i], bfr[j], acc[i][j], 0, 0, 0);
        __syncthreads();
    }

    // epilogue: C/D mapping col = lane&15, row = (lane>>4)*4 + reg
#pragma unroll
    for (int j = 0; j < 4; ++j) {
        const int n = n0 + wn + j * 16 + lrow;
        const float bb = (n < nsplit) ? bias[n] : bias2[n - nsplit];
#pragma unroll
        for (int i = 0; i < 4; ++i) {
            const int mrow = m0 + wm + i * 16 + kq * 4;
#pragma unroll
            for (int r = 0; r < 4; ++r) {
                const float v = acc[i][j][r] + bb;
                if constexpr (std::is_same<TOut, float>::value) {
                    C[(size_t)(mrow + r) * N + n] = v;
                } else {
                    C[(size_t)(mrow + r) * N + n] = f2bf(v);
                }
            }
        }
    }
}

// ---------------------------------------------------------------------------
// Deformable sampling v3: block = 8 queries x 32 workers.
// LDS: s_pk (16KB, one 16B entry/sample: 4 u16 idx + 4 bf16 folded weights)
// ALIASES the phase-A buffers (s_off/s_logit/s_aw) -- A2 stages its reads to
// registers, barriers, then overwrites. Conflict-free swizzle (2-way max).
// oa: f32 [B*LQ][384] = offsets(256) | attn logits(128).
// ---------------------------------------------------------------------------
#define QB 8
__global__ __launch_bounds__(256) void msda_sample3(const unsigned short* __restrict__ value,
                                                    const float* __restrict__ oa,
                                                    const float* __restrict__ refp,
                                                    unsigned short* __restrict__ samp) {
    __shared__ char smem[16384 + 256];
    unsigned int* s_pk   = (unsigned int*)smem;          // 16KB (phase B)
    float* s_off   = (float*)smem;                        // 8KB  (phase A)
    float* s_logit = (float*)(smem + 8192);               // 4KB  (phase A)
    float* s_aw    = (float*)(smem + 12288);              // 4KB  (phase A)
    float* s_ref   = (float*)(smem + 16384);              // 256B (phase A)

    const int t = threadIdx.x;
    // XCD-aware remap: XCD k = bid%8 serves a contiguous q range (one batch)
    const int j = blockIdx.x;
    const int bq0 = ((j & 7) * 680 + (j >> 3)) * QB;
    const int b = bq0 / LQ_;

    // phase 0: stage per-query data (nontemporal -- streaming, don't pollute L2)
    {
        const float* oab = oa + (size_t)bq0 * 384;
#pragma unroll
        for (int r = 0; r < 2; ++r) {
            const int i = t + r * 256;        // 0..511
            const int ql = i >> 6, c = i & 63;
            ((f32x4*)s_off)[ql * 64 + c] =
                __builtin_nontemporal_load((const f32x4*)(oab + (size_t)ql * 384) + c);
        }
        {
            const int ql = t >> 5, c = t & 31;
            ((f32x4*)s_logit)[ql * 32 + c] =
                __builtin_nontemporal_load((const f32x4*)(oab + (size_t)ql * 384 + 256) + c);
        }
        if (t < 16)
            ((f32x4*)s_ref)[t] = __builtin_nontemporal_load((const f32x4*)(refp + (size_t)bq0 * 8) + t);
    }
    __syncthreads();

    // phase A1: 64 softmaxes (q,h) over 16 logits
    if (t < 64) {
        const float* lg = s_logit + (t >> 3) * 128 + (t & 7) * 16;
        float m = -1e30f;
#pragma unroll
        for (int i = 0; i < 16; ++i) m = fmaxf(m, lg[i]);
        float e[16], s = 0.f;
#pragma unroll
        for (int i = 0; i < 16; ++i) { e[i] = __expf(lg[i] - m); s += e[i]; }
        const float inv = 1.f / s;
#pragma unroll
        for (int i = 0; i < 16; ++i) s_aw[t * 16 + i] = e[i] * inv;
    }
    __syncthreads();

    // phase A2: 4 samples/thread -> registers (reads s_off/s_ref/s_aw)
    unsigned int pk0[4], pk1[4], pk2[4], pk3[4];
    {
        const int Wls[4] = {128, 64, 32, 16};
        const int Hls[4] = {128, 64, 32, 16};
        const int st_[4] = {0, 16384, 20480, 21504};
#pragma unroll
        for (int ii = 0; ii < 4; ++ii) {
            const int s = t * 4 + ii;
            const int q = s >> 7;
            const int rest = s & 127;        // h*16 + l*4 + p
            const int h = rest >> 4;
            const int l = (rest >> 2) & 3;
            const int Wl = Wls[l], Hl = Hls[l], base = st_[l];
            const float ix = s_ref[q * 8 + l * 2]     * (float)Wl - 0.5f + s_off[q * 256 + rest * 2];
            const float iy = s_ref[q * 8 + l * 2 + 1] * (float)Hl - 0.5f + s_off[q * 256 + rest * 2 + 1];
            const float fix = floorf(ix), fiy = floorf(iy);
            const int x0 = (int)fix, y0 = (int)fiy;
            const int x1 = x0 + 1, y1 = y0 + 1;
            const float fx = ix - fix, fy = iy - fiy;
            const bool vx0 = (x0 >= 0) & (x0 < Wl);
            const bool vx1 = (x1 >= 0) & (x1 < Wl);
            const bool vy0 = (y0 >= 0) & (y0 < Hl);
            const bool vy1 = (y1 >= 0) & (y1 < Hl);
            const int cx0 = min(max(x0, 0), Wl - 1);
            const int cx1 = min(max(x1, 0), Wl - 1);
            const int cy0 = min(max(y0, 0), Hl - 1);
            const int cy1 = min(max(y1, 0), Hl - 1);
            const float aw = s_aw[(q * 8 + h) * 16 + (rest & 15)];
            const float w00 = aw * (1.f - fx) * (1.f - fy) * (float)(vx0 && vy0);
            const float w01 = aw * fx * (1.f - fy)         * (float)(vx1 && vy0);
            const float w10 = aw * (1.f - fx) * fy         * (float)(vx0 && vy1);
            const float w11 = aw * fx * fy                 * (float)(vx1 && vy1);
            pk0[ii] = (unsigned int)(base + cy0 * Wl + cx0) | ((unsigned int)(base + cy0 * Wl + cx1) << 16);
            pk1[ii] = (unsigned int)(base + cy1 * Wl + cx0) | ((unsigned int)(base + cy1 * Wl + cx1) << 16);
            pk2[ii] = pk2bf(w00, w01);
            pk3[ii] = pk2bf(w10, w11);
        }
    }
    __syncthreads();  // all phase-A reads done; safe to overwrite aliased region

#pragma unroll
    for (int ii = 0; ii < 4; ++ii) {
        const int s = t * 4 + ii;
        const int q = s >> 7;
        const int h = (s >> 4) & 7;
        const int swz = ((h & 3) << 2) ^ ((((h >> 2) ^ (q & 1)) & 1) << 4);
        *(uint4*)&s_pk[(s * 4) ^ swz] = make_uint4(pk0[ii], pk1[ii], pk2[ii], pk3[ii]);
    }
    __syncthreads();

    // phase B: gather + accumulate. worker = (h, dg), 8 channels each
    const int q = t >> 5;
    const int w = t & 31;
    const int h = w >> 2;
    const int dg = w & 3;
    const int swz = ((h & 3) << 2) ^ ((((h >> 2) ^ (q & 1)) & 1) << 4);
    const unsigned short* vbase = value + (size_t)b * LEN_ * DM + h * HD + dg * 8;

    float acc[8] = {0.f, 0.f, 0.f, 0.f, 0.f, 0.f, 0.f, 0.f};
    const int sbase = q * 128 + h * 16;
#pragma unroll
    for (int lp = 0; lp < 16; ++lp) {
        const uint4 pk = *(const uint4*)&s_pk[((sbase + lp) * 4) ^ swz];
        const uint4 v00 = *(const uint4*)(vbase + (size_t)(pk.x & 0xffffu) * DM);
        const uint4 v01 = *(const uint4*)(vbase + (size_t)(pk.x >> 16) * DM);
        const uint4 v10 = *(const uint4*)(vbase + (size_t)(pk.y & 0xffffu) * DM);
        const uint4 v11 = *(const uint4*)(vbase + (size_t)(pk.y >> 16) * DM);
        const float w00 = __uint_as_float(pk.z << 16);
        const float w01 = __uint_as_float(pk.z & 0xffff0000u);
        const float w10 = __uint_as_float(pk.w << 16);
        const float w11 = __uint_as_float(pk.w & 0xffff0000u);
#pragma unroll
        for (int c = 0; c < 4; ++c) {
            const unsigned int u00 = (&v00.x)[c], u01 = (&v01.x)[c];
            const unsigned int u10 = (&v10.x)[c], u11 = (&v11.x)[c];
            float a0 = acc[c * 2], a1 = acc[c * 2 + 1];
            a0 = fmaf(w00, __uint_as_float(u00 << 16), a0);
            a1 = fmaf(w00, __uint_as_float(u00 & 0xffff0000u), a1);
            a0 = fmaf(w01, __uint_as_float(u01 << 16), a0);
            a1 = fmaf(w01, __uint_as_float(u01 & 0xffff0000u), a1);
            a0 = fmaf(w10, __uint_as_float(u10 << 16), a0);
            a1 = fmaf(w10, __uint_as_float(u10 & 0xffff0000u), a1);
            a0 = fmaf(w11, __uint_as_float(u11 << 16), a0);
            a1 = fmaf(w11, __uint_as_float(u11 & 0xffff0000u), a1);
            acc[c * 2] = a0;
            acc[c * 2 + 1] = a1;
        }
    }
    u32x4 o;
    o.x = pk2bf(acc[0], acc[1]);
    o.y = pk2bf(acc[2], acc[3]);
    o.z = pk2bf(acc[4], acc[5]);
    o.w = pk2bf(acc[6], acc[7]);
    __builtin_nontemporal_store(o, (u32x4*)(samp + (size_t)(bq0 + q) * 256 + h * HD + dg * 8));
}

extern "C" void kernel_launch(void* const* d_in, const int* in_sizes, int n_in,
                              void* d_out, int out_size, void* d_ws, size_t ws_size,
                              hipStream_t stream) {
    const float* query  = (const float*)d_in[0];
    const float* refp   = (const float*)d_in[1];
    const float* inpf   = (const float*)d_in[2];
    const float* W_off  = (const float*)d_in[3];
    const float* b_off  = (const float*)d_in[4];
    const float* W_attn = (const float*)d_in[5];
    const float* b_attn = (const float*)d_in[6];
    const float* W_val  = (const float*)d_in[7];
    const float* b_val  = (const float*)d_in[8];
    const float* W_out  = (const float*)d_in[9];
    const float* b_out  = (const float*)d_in[10];
    float* out = (float*)d_out;

    char* ws = (char*)d_ws;
    unsigned short* val_bf  = (unsigned short*)(ws + WS_VAL);
    unsigned short* q_bf    = (unsigned short*)(ws + WS_QBF);
    unsigned short* in_bf   = (unsigned short*)(ws + WS_INBF);
    unsigned short* samp_bf = (unsigned short*)(ws + WS_INBF);  // reuse after value GEMM
    float* oa = (float*)(ws + WS_OA);
    unsigned short* Wt_val = (unsigned short*)(ws + WS_WT);
    unsigned short* Wt_oa  = (unsigned short*)(ws + WS_WT + 131072);  // 384 rows x 256
    unsigned short* Wt_out = (unsigned short*)(ws + WS_WT + 327680);

    const int M = B_ * LQ_;          // 43520
    const int n4 = M * DM / 4;

    // converts + weight transposes
    cvt_bf16<<<dim3((n4 + 255) / 256), 256, 0, stream>>>(inpf, in_bf, n4);
    cvt_bf16<<<dim3((n4 + 255) / 256), 256, 0, stream>>>(query, q_bf, n4);
    wt_cvt<<<dim3(16, 16), 256, 0, stream>>>(W_val, Wt_val, 256, 256);
    wt_cvt<<<dim3(16, 16), 256, 0, stream>>>(W_off, Wt_oa, 256, 256);                  // rows 0..255
    wt_cvt<<<dim3(8, 16), 256, 0, stream>>>(W_attn, Wt_oa + 256 * 256, 256, 128);      // rows 256..383
    wt_cvt<<<dim3(16, 16), 256, 0, stream>>>(W_out, Wt_out, 256, 256);

    // GEMMs (MFMA bf16)
    gemm_mfma<unsigned short><<<dim3(M / 128, 2), 256, 0, stream>>>(
        in_bf, Wt_val, b_val, b_val, 256, val_bf, M, 256, 256);
    gemm_mfma<float><<<dim3(M / 128, 3), 256, 0, stream>>>(
        q_bf, Wt_oa, b_off, b_attn, 256, oa, M, 384, 256);

    // sampling
    msda_sample3<<<dim3(M / QB), 256, 0, stream>>>(val_bf, oa, refp, samp_bf);

    // output projection
    gemm_mfma<float><<<dim3(M / 128, 2), 256, 0, stream>>>(
        samp_bf, Wt_out, b_out, b_out, 256, out, M, 256, 256);
}

// Round 4
// 296.455 us; speedup vs baseline: 2.4760x; 1.1067x over previous
//
#include <hip/hip_runtime.h>
#include <hip/hip_bf16.h>
#include <hip/hip_fp16.h>
#include <type_traits>

// ---- problem constants ----
#define B_    2
#define LQ_   21760
#define LEN_  21760
#define DM    256
#define NH    8
#define NL    4
#define NP    4
#define HD    32

// workspace layout (bytes)
#define WS_VAL   0u            // f16 value [B*LEN][256]           22,282,240
#define WS_SAMP  22282240u     // bf16 sampled [B*LQ][256]         22,282,240
#define WS_OA    44564480u     // f16 off|attn [B*LQ][384]         33,423,360
#define WS_WT    77987840u     // bf16 W^T arena: val|oa|out        458,752

typedef __attribute__((ext_vector_type(4))) float f32x4;
typedef __attribute__((ext_vector_type(8))) short bf16x8;
typedef __attribute__((ext_vector_type(4))) unsigned int u32x4;
typedef __attribute__((ext_vector_type(2))) unsigned int u32x2;

__device__ __forceinline__ unsigned short f2bf(float v) {
    __hip_bfloat16 h = __float2bfloat16(v);
    return *reinterpret_cast<unsigned short*>(&h);
}
__device__ __forceinline__ unsigned int pk2bf(float a, float b) {
    return (unsigned int)f2bf(a) | ((unsigned int)f2bf(b) << 16);
}
__device__ __forceinline__ unsigned int pk2h(float a, float b) {
    __half2 h = __floats2half2_rn(a, b);
    union { __half2 h; unsigned int u; } c; c.h = h; return c.u;
}
__device__ __forceinline__ __half2 u2h2(unsigned int u) {
    union { unsigned int u; __half2 h; } c; c.u = u; return c.h;
}

// ---------------------------------------------------------------------------
// All four weight transposes in one dispatch. W[K=256,N] f32 -> Wt[N,256] bf16.
// grid (16, 16, 4); matrix 2 (W_attn, N=128) idles half its x-blocks.
// ---------------------------------------------------------------------------
__global__ __launch_bounds__(256) void wt_cvt_all(const float* __restrict__ Wv,
                                                  const float* __restrict__ Wo,
                                                  const float* __restrict__ Wa,
                                                  const float* __restrict__ Wu,
                                                  unsigned short* __restrict__ wt) {
    const float* Ws[4] = {Wv, Wo, Wa, Wu};
    const int Ns[4] = {256, 256, 128, 256};
    const unsigned int dof[4] = {0u, 65536u, 131072u, 163840u};
    const int m = blockIdx.z;
    const int n0 = blockIdx.x * 16, k0 = blockIdx.y * 16;
    if (n0 >= Ns[m]) return;
    __shared__ float tile[16][17];
    const int tx = threadIdx.x & 15, ty = threadIdx.x >> 4;
    tile[ty][tx] = Ws[m][(size_t)(k0 + ty) * Ns[m] + n0 + tx];
    __syncthreads();
    wt[dof[m] + (size_t)(n0 + ty) * 256 + k0 + tx] = f2bf(tile[tx][ty]);
}

// ---------------------------------------------------------------------------
// MFMA bf16 GEMM: C[M,N] = A @ Wt^T + bias. 128x128 tile, BK=32, 4 waves.
// AF32: A is f32, converted to bf16 during LDS staging (regs + ds_write).
// else: A is bf16, staged via global_load_lds. TOut in {float, __half, ushort/bf16}.
// ---------------------------------------------------------------------------
template <bool AF32, typename TOut>
__global__ __launch_bounds__(256) void gemm_mfma(const void* __restrict__ Av,
                                                 const unsigned short* __restrict__ Bt,
                                                 const float* __restrict__ bias,
                                                 const float* __restrict__ bias2,
                                                 int nsplit,
                                                 TOut* __restrict__ C,
                                                 int M, int N, int K) {
    __shared__ unsigned short As[128 * 32];  // [m][k] bf16, 64B rows
    __shared__ unsigned short Bs[128 * 32];  // [n][k] bf16
    const int t = threadIdx.x;
    const int wv = t >> 6;
    const int ln = t & 63;
    const int m0 = blockIdx.x * 128;
    const int n0 = blockIdx.y * 128;
    const int wm = (wv & 1) * 64;
    const int wn = (wv >> 1) * 64;
    const int lrow = ln & 15;
    const int kq = ln >> 4;

    f32x4 acc[4][4] = {};

    for (int k0 = 0; k0 < K; k0 += 32) {
        if constexpr (AF32) {
            const float* Af = (const float*)Av;
#pragma unroll
            for (int c = 0; c < 4; ++c) {
                const int i = t + c * 256;      // 0..1023
                const int row = i >> 3;         // 0..127
                const int kq4 = (i & 7) * 4;    // 0..28
                f32x4 v = *(const f32x4*)&Af[(size_t)(m0 + row) * K + k0 + kq4];
                uint2 p = make_uint2(pk2bf(v.x, v.y), pk2bf(v.z, v.w));
                *(uint2*)((char*)As + row * 64 + kq4 * 2) = p;
            }
#pragma unroll
            for (int c = 0; c < 2; ++c) {
                const int o = c * 4096 + t * 16;
                const int row = o >> 6;
                const int ke = (o & 63) >> 1;
                const unsigned short* gb = Bt + (size_t)(n0 + row) * K + k0 + ke;
                __builtin_amdgcn_global_load_lds(
                    (const __attribute__((address_space(1))) void*)gb,
                    (__attribute__((address_space(3))) void*)((char*)Bs + o), 16, 0, 0);
            }
        } else {
            const unsigned short* Ab = (const unsigned short*)Av;
#pragma unroll
            for (int c = 0; c < 2; ++c) {
                const int o = c * 4096 + t * 16;
                const int row = o >> 6;
                const int ke = (o & 63) >> 1;
                const unsigned short* ga = Ab + (size_t)(m0 + row) * K + k0 + ke;
                const unsigned short* gb = Bt + (size_t)(n0 + row) * K + k0 + ke;
                __builtin_amdgcn_global_load_lds(
                    (const __attribute__((address_space(1))) void*)ga,
                    (__attribute__((address_space(3))) void*)((char*)As + o), 16, 0, 0);
                __builtin_amdgcn_global_load_lds(
                    (const __attribute__((address_space(1))) void*)gb,
                    (__attribute__((address_space(3))) void*)((char*)Bs + o), 16, 0, 0);
            }
        }
        __syncthreads();

        bf16x8 af[4], bfr[4];
#pragma unroll
        for (int i = 0; i < 4; ++i) {
            af[i]  = *(const bf16x8*)((char*)As + (wm + i * 16 + lrow) * 64 + kq * 16);
            bfr[i] = *(const bf16x8*)((char*)Bs + (wn + i * 16 + lrow) * 64 + kq * 16);
        }
#pragma unroll
        for (int i = 0; i < 4; ++i)
#pragma unroll
            for (int j = 0; j < 4; ++j)
                acc[i][j] = __builtin_amdgcn_mfma_f32_16x16x32_bf16(af[i], bfr[j], acc[i][j], 0, 0, 0);
        __syncthreads();
    }

    // epilogue: C/D mapping col = lane&15, row = (lane>>4)*4 + reg
#pragma unroll
    for (int j = 0; j < 4; ++j) {
        const int n = n0 + wn + j * 16 + lrow;
        const float bb = (n < nsplit) ? bias[n] : bias2[n - nsplit];
#pragma unroll
        for (int i = 0; i < 4; ++i) {
            const int mrow = m0 + wm + i * 16 + kq * 4;
#pragma unroll
            for (int r = 0; r < 4; ++r) {
                const float v = acc[i][j][r] + bb;
                if constexpr (std::is_same<TOut, float>::value) {
                    C[(size_t)(mrow + r) * N + n] = v;
                } else if constexpr (std::is_same<TOut, __half>::value) {
                    C[(size_t)(mrow + r) * N + n] = __float2half(v);
                } else {
                    C[(size_t)(mrow + r) * N + n] = f2bf(v);
                }
            }
        }
    }
}

// ---------------------------------------------------------------------------
// Deformable sampling v4: block = 8 queries x 32 workers. value/oa in f16.
// Phase B: unroll x2, 8 gathers staged before FMAs (MLP), fma_mix on f16.
// ---------------------------------------------------------------------------
#define QB 8
__device__ __forceinline__ void accum4(const uint4& v, float w, float* acc) {
#pragma unroll
    for (int c = 0; c < 4; ++c) {
        const __half2 h = u2h2((&v.x)[c]);
        acc[c * 2]     = fmaf(w, __low2float(h),  acc[c * 2]);
        acc[c * 2 + 1] = fmaf(w, __high2float(h), acc[c * 2 + 1]);
    }
}

__global__ __launch_bounds__(256) void msda_sample4(const unsigned short* __restrict__ value,
                                                    const unsigned short* __restrict__ oa,
                                                    const float* __restrict__ refp,
                                                    unsigned short* __restrict__ samp) {
    __shared__ char smem[16384 + 256];
    unsigned int* s_pk = (unsigned int*)smem;             // 16KB (phase B)
    float* s_off   = (float*)smem;                        // 8KB  (phase A)
    float* s_logit = (float*)(smem + 8192);               // 4KB  (phase A)
    float* s_aw    = (float*)(smem + 12288);              // 4KB  (phase A)
    float* s_ref   = (float*)(smem + 16384);              // 256B

    const int t = threadIdx.x;
    const int j = blockIdx.x;
    const int bq0 = ((j & 7) * 680 + (j >> 3)) * QB;
    const int b = bq0 / LQ_;

    // phase 0: stage (f16 -> f32 in LDS), nontemporal
    {
        const unsigned short* oab = oa + (size_t)bq0 * 384;
        {
            const int ql = t >> 5, c = t & 31;   // 8 halves each
            u32x4 raw = __builtin_nontemporal_load((const u32x4*)(oab + (size_t)ql * 384) + c);
            float2 f0 = __half22float2(u2h2(raw.x));
            float2 f1 = __half22float2(u2h2(raw.y));
            float2 f2 = __half22float2(u2h2(raw.z));
            float2 f3 = __half22float2(u2h2(raw.w));
            f32x4 o0 = {f0.x, f0.y, f1.x, f1.y};
            f32x4 o1 = {f2.x, f2.y, f3.x, f3.y};
            ((f32x4*)s_off)[ql * 64 + c * 2] = o0;
            ((f32x4*)s_off)[ql * 64 + c * 2 + 1] = o1;
        }
        {
            const int ql = t >> 5, c = t & 31;   // 4 halves each
            u32x2 raw = __builtin_nontemporal_load((const u32x2*)(oab + (size_t)ql * 384 + 256) + c);
            float2 f0 = __half22float2(u2h2(raw.x));
            float2 f1 = __half22float2(u2h2(raw.y));
            f32x4 o0 = {f0.x, f0.y, f1.x, f1.y};
            ((f32x4*)s_logit)[ql * 32 + c] = o0;
        }
        if (t < 16)
            ((f32x4*)s_ref)[t] = __builtin_nontemporal_load((const f32x4*)(refp + (size_t)bq0 * 8) + t);
    }
    __syncthreads();

    // phase A1: 64 softmaxes (q,h) over 16 logits
    if (t < 64) {
        const float* lg = s_logit + (t >> 3) * 128 + (t & 7) * 16;
        float m = -1e30f;
#pragma unroll
        for (int i = 0; i < 16; ++i) m = fmaxf(m, lg[i]);
        float e[16], s = 0.f;
#pragma unroll
        for (int i = 0; i < 16; ++i) { e[i] = __expf(lg[i] - m); s += e[i]; }
        const float inv = 1.f / s;
#pragma unroll
        for (int i = 0; i < 16; ++i) s_aw[t * 16 + i] = e[i] * inv;
    }
    __syncthreads();

    // phase A2: 4 samples/thread -> registers
    unsigned int pk0[4], pk1[4], pk2[4], pk3[4];
    {
        const int Wls[4] = {128, 64, 32, 16};
        const int Hls[4] = {128, 64, 32, 16};
        const int st_[4] = {0, 16384, 20480, 21504};
#pragma unroll
        for (int ii = 0; ii < 4; ++ii) {
            const int s = t * 4 + ii;
            const int q = s >> 7;
            const int rest = s & 127;        // h*16 + l*4 + p
            const int h = rest >> 4;
            const int l = (rest >> 2) & 3;
            const int Wl = Wls[l], Hl = Hls[l], base = st_[l];
            const float ix = s_ref[q * 8 + l * 2]     * (float)Wl - 0.5f + s_off[q * 256 + rest * 2];
            const float iy = s_ref[q * 8 + l * 2 + 1] * (float)Hl - 0.5f + s_off[q * 256 + rest * 2 + 1];
            const float fix = floorf(ix), fiy = floorf(iy);
            const int x0 = (int)fix, y0 = (int)fiy;
            const int x1 = x0 + 1, y1 = y0 + 1;
            const float fx = ix - fix, fy = iy - fiy;
            const bool vx0 = (x0 >= 0) & (x0 < Wl);
            const bool vx1 = (x1 >= 0) & (x1 < Wl);
            const bool vy0 = (y0 >= 0) & (y0 < Hl);
            const bool vy1 = (y1 >= 0) & (y1 < Hl);
            const int cx0 = min(max(x0, 0), Wl - 1);
            const int cx1 = min(max(x1, 0), Wl - 1);
            const int cy0 = min(max(y0, 0), Hl - 1);
            const int cy1 = min(max(y1, 0), Hl - 1);
            const float aw = s_aw[(q * 8 + h) * 16 + (rest & 15)];
            const float w00 = aw * (1.f - fx) * (1.f - fy) * (float)(vx0 && vy0);
            const float w01 = aw * fx * (1.f - fy)         * (float)(vx1 && vy0);
            const float w10 = aw * (1.f - fx) * fy         * (float)(vx0 && vy1);
            const float w11 = aw * fx * fy                 * (float)(vx1 && vy1);
            pk0[ii] = (unsigned int)(base + cy0 * Wl + cx0) | ((unsigned int)(base + cy0 * Wl + cx1) << 16);
            pk1[ii] = (unsigned int)(base + cy1 * Wl + cx0) | ((unsigned int)(base + cy1 * Wl + cx1) << 16);
            pk2[ii] = pk2h(w00, w01);
            pk3[ii] = pk2h(w10, w11);
        }
    }
    __syncthreads();  // phase-A reads done; safe to overwrite aliased region

#pragma unroll
    for (int ii = 0; ii < 4; ++ii) {
        const int s = t * 4 + ii;
        const int q = s >> 7;
        const int h = (s >> 4) & 7;
        const int swz = ((h & 3) << 2) ^ ((((h >> 2) ^ (q & 1)) & 1) << 4);
        *(uint4*)&s_pk[(s * 4) ^ swz] = make_uint4(pk0[ii], pk1[ii], pk2[ii], pk3[ii]);
    }
    __syncthreads();

    // phase B: worker = (h, dg); unroll x2, stage 8 gathers before FMAs
    const int q = t >> 5;
    const int w = t & 31;
    const int h = w >> 2;
    const int dg = w & 3;
    const int swz = ((h & 3) << 2) ^ ((((h >> 2) ^ (q & 1)) & 1) << 4);
    const unsigned short* vbase = value + (size_t)b * LEN_ * DM + h * HD + dg * 8;

    float acc[8] = {0.f, 0.f, 0.f, 0.f, 0.f, 0.f, 0.f, 0.f};
    const int sbase = q * 128 + h * 16;
#pragma unroll
    for (int lp2 = 0; lp2 < 8; ++lp2) {
        const uint4 pkA = *(const uint4*)&s_pk[((sbase + 2 * lp2)     * 4) ^ swz];
        const uint4 pkB = *(const uint4*)&s_pk[((sbase + 2 * lp2 + 1) * 4) ^ swz];
        const uint4 a00 = *(const uint4*)(vbase + (size_t)(pkA.x & 0xffffu) * DM);
        const uint4 a01 = *(const uint4*)(vbase + (size_t)(pkA.x >> 16) * DM);
        const uint4 a10 = *(const uint4*)(vbase + (size_t)(pkA.y & 0xffffu) * DM);
        const uint4 a11 = *(const uint4*)(vbase + (size_t)(pkA.y >> 16) * DM);
        const uint4 b00 = *(const uint4*)(vbase + (size_t)(pkB.x & 0xffffu) * DM);
        const uint4 b01 = *(const uint4*)(vbase + (size_t)(pkB.x >> 16) * DM);
        const uint4 b10 = *(const uint4*)(vbase + (size_t)(pkB.y & 0xffffu) * DM);
        const uint4 b11 = *(const uint4*)(vbase + (size_t)(pkB.y >> 16) * DM);
        const __half2 wA0 = u2h2(pkA.z), wA1 = u2h2(pkA.w);
        const __half2 wB0 = u2h2(pkB.z), wB1 = u2h2(pkB.w);
        accum4(a00, __low2float(wA0),  acc);
        accum4(a01, __high2float(wA0), acc);
        accum4(a10, __low2float(wA1),  acc);
        accum4(a11, __high2float(wA1), acc);
        accum4(b00, __low2float(wB0),  acc);
        accum4(b01, __high2float(wB0), acc);
        accum4(b10, __low2float(wB1),  acc);
        accum4(b11, __high2float(wB1), acc);
    }
    u32x4 o;
    o.x = pk2bf(acc[0], acc[1]);
    o.y = pk2bf(acc[2], acc[3]);
    o.z = pk2bf(acc[4], acc[5]);
    o.w = pk2bf(acc[6], acc[7]);
    __builtin_nontemporal_store(o, (u32x4*)(samp + (size_t)(bq0 + q) * 256 + h * HD + dg * 8));
}

extern "C" void kernel_launch(void* const* d_in, const int* in_sizes, int n_in,
                              void* d_out, int out_size, void* d_ws, size_t ws_size,
                              hipStream_t stream) {
    const float* query  = (const float*)d_in[0];
    const float* refp   = (const float*)d_in[1];
    const float* inpf   = (const float*)d_in[2];
    const float* W_off  = (const float*)d_in[3];
    const float* b_off  = (const float*)d_in[4];
    const float* W_attn = (const float*)d_in[5];
    const float* b_attn = (const float*)d_in[6];
    const float* W_val  = (const float*)d_in[7];
    const float* b_val  = (const float*)d_in[8];
    const float* W_out  = (const float*)d_in[9];
    const float* b_out  = (const float*)d_in[10];
    float* out = (float*)d_out;

    char* ws = (char*)d_ws;
    unsigned short* val_h  = (unsigned short*)(ws + WS_VAL);
    unsigned short* samp_bf = (unsigned short*)(ws + WS_SAMP);
    unsigned short* oa_h   = (unsigned short*)(ws + WS_OA);
    unsigned short* wt     = (unsigned short*)(ws + WS_WT);
    unsigned short* Wt_val = wt;
    unsigned short* Wt_oa  = wt + 65536;
    unsigned short* Wt_out = wt + 163840;

    const int M = B_ * LQ_;          // 43520

    // all weight transposes in one dispatch
    wt_cvt_all<<<dim3(16, 16, 4), 256, 0, stream>>>(W_val, W_off, W_attn, W_out, wt);

    // value = input @ W_val + b_val  (A f32 -> staged bf16; out f16)
    gemm_mfma<true, __half><<<dim3(M / 128, 2), 256, 0, stream>>>(
        inpf, Wt_val, b_val, b_val, 256, (__half*)val_h, M, 256, 256);
    // off|attn = query @ [W_off|W_attn] (out f16)
    gemm_mfma<true, __half><<<dim3(M / 128, 3), 256, 0, stream>>>(
        query, Wt_oa, b_off, b_attn, 256, (__half*)oa_h, M, 384, 256);

    // sampling
    msda_sample4<<<dim3(M / QB), 256, 0, stream>>>(val_h, oa_h, refp, samp_bf);

    // out = sampled @ W_out + b_out (A bf16 via global_load_lds; out f32)
    gemm_mfma<false, float><<<dim3(M / 128, 2), 256, 0, stream>>>(
        samp_bf, Wt_out, b_out, b_out, 256, out, M, 256, 256);
}

// Round 5
// 290.053 us; speedup vs baseline: 2.5307x; 1.0221x over previous
//
#include <hip/hip_runtime.h>
#include <hip/hip_bf16.h>
#include <hip/hip_fp16.h>
#include <type_traits>

// ---- problem constants ----
#define B_    2
#define LQ_   21760
#define LEN_  21760
#define DM    256
#define NH    8
#define NL    4
#define NP    4
#define HD    32

// workspace layout (bytes)
#define WS_VAL   0u            // f16 value [B][H][21760][32]      22,282,240
#define WS_SAMP  22282240u     // bf16 sampled [B*LQ][256]         22,282,240
#define WS_OA    44564480u     // f16 off|attn [B*LQ][384]         33,423,360
#define WS_WT    77987840u     // bf16 W^T arena: val|oa|out        458,752

typedef __attribute__((ext_vector_type(4))) float f32x4;
typedef __attribute__((ext_vector_type(8))) short bf16x8;
typedef __attribute__((ext_vector_type(4))) unsigned int u32x4;
typedef __attribute__((ext_vector_type(2))) unsigned int u32x2;

__device__ __forceinline__ unsigned short f2bf(float v) {
    __hip_bfloat16 h = __float2bfloat16(v);
    return *reinterpret_cast<unsigned short*>(&h);
}
__device__ __forceinline__ unsigned int pk2bf(float a, float b) {
    return (unsigned int)f2bf(a) | ((unsigned int)f2bf(b) << 16);
}
__device__ __forceinline__ unsigned int pk2h(float a, float b) {
    __half2 h = __floats2half2_rn(a, b);
    union { __half2 h; unsigned int u; } c; c.h = h; return c.u;
}
__device__ __forceinline__ __half2 u2h2(unsigned int u) {
    union { unsigned int u; __half2 h; } c; c.u = u; return c.h;
}

// ---------------------------------------------------------------------------
// All four weight transposes in one dispatch. W[K=256,N] f32 -> Wt[N,256] bf16.
// ---------------------------------------------------------------------------
__global__ __launch_bounds__(256) void wt_cvt_all(const float* __restrict__ Wv,
                                                  const float* __restrict__ Wo,
                                                  const float* __restrict__ Wa,
                                                  const float* __restrict__ Wu,
                                                  unsigned short* __restrict__ wt) {
    const float* Ws[4] = {Wv, Wo, Wa, Wu};
    const int Ns[4] = {256, 256, 128, 256};
    const unsigned int dof[4] = {0u, 65536u, 131072u, 163840u};
    const int m = blockIdx.z;
    const int n0 = blockIdx.x * 16, k0 = blockIdx.y * 16;
    if (n0 >= Ns[m]) return;
    __shared__ float tile[16][17];
    const int tx = threadIdx.x & 15, ty = threadIdx.x >> 4;
    tile[ty][tx] = Ws[m][(size_t)(k0 + ty) * Ns[m] + n0 + tx];
    __syncthreads();
    wt[dof[m] + (size_t)(n0 + ty) * 256 + k0 + tx] = f2bf(tile[tx][ty]);
}

// ---------------------------------------------------------------------------
// Merged pre-GEMMs (one dispatch, 2 jobs):
//  job0 (x=0..1): value = inpf @ Wt_val + b_val -> f16, PERMUTED [b][h][pix][32]
//  job1 (x=2..4): oa    = query @ Wt_oa + (b_off|b_attn) -> f16 flat [bq][384]
// 128x128 tile, BK=32, 4 waves. A is f32, converted to bf16 during staging.
// grid (5, 340).
// ---------------------------------------------------------------------------
__global__ __launch_bounds__(256) void gemm_pre(const float* __restrict__ inpf,
                                                const float* __restrict__ query,
                                                const unsigned short* __restrict__ Wt_val,
                                                const unsigned short* __restrict__ Wt_oa,
                                                const float* __restrict__ b_val,
                                                const float* __restrict__ b_off,
                                                const float* __restrict__ b_attn,
                                                unsigned short* __restrict__ val_h,
                                                unsigned short* __restrict__ oa_h) {
    __shared__ unsigned short As[128 * 32];
    __shared__ unsigned short Bs[128 * 32];
    const int t = threadIdx.x;
    const int wv = t >> 6;
    const int ln = t & 63;
    const int job = (blockIdx.x >= 2);
    const int n0 = (job ? (blockIdx.x - 2) : blockIdx.x) * 128;
    const int m0 = blockIdx.y * 128;
    const float* A = job ? query : inpf;
    const unsigned short* Bt = job ? Wt_oa : Wt_val;
    const int K = 256;
    const int wm = (wv & 1) * 64;
    const int wn = (wv >> 1) * 64;
    const int lrow = ln & 15;
    const int kq = ln >> 4;

    f32x4 acc[4][4] = {};

    for (int k0 = 0; k0 < K; k0 += 32) {
#pragma unroll
        for (int c = 0; c < 4; ++c) {
            const int i = t + c * 256;
            const int row = i >> 3;
            const int kq4 = (i & 7) * 4;
            f32x4 v = *(const f32x4*)&A[(size_t)(m0 + row) * K + k0 + kq4];
            uint2 p = make_uint2(pk2bf(v.x, v.y), pk2bf(v.z, v.w));
            *(uint2*)((char*)As + row * 64 + kq4 * 2) = p;
        }
#pragma unroll
        for (int c = 0; c < 2; ++c) {
            const int o = c * 4096 + t * 16;
            const int row = o >> 6;
            const int ke = (o & 63) >> 1;
            const unsigned short* gb = Bt + (size_t)(n0 + row) * K + k0 + ke;
            __builtin_amdgcn_global_load_lds(
                (const __attribute__((address_space(1))) void*)gb,
                (__attribute__((address_space(3))) void*)((char*)Bs + o), 16, 0, 0);
        }
        __syncthreads();

        bf16x8 af[4], bfr[4];
#pragma unroll
        for (int i = 0; i < 4; ++i) {
            af[i]  = *(const bf16x8*)((char*)As + (wm + i * 16 + lrow) * 64 + kq * 16);
            bfr[i] = *(const bf16x8*)((char*)Bs + (wn + i * 16 + lrow) * 64 + kq * 16);
        }
#pragma unroll
        for (int i = 0; i < 4; ++i)
#pragma unroll
            for (int j = 0; j < 4; ++j)
                acc[i][j] = __builtin_amdgcn_mfma_f32_16x16x32_bf16(af[i], bfr[j], acc[i][j], 0, 0, 0);
        __syncthreads();
    }

    // epilogue: C/D mapping col = lane&15, row = (lane>>4)*4 + reg
    const int b = m0 / LQ_;       // block never straddles batch (21760 % 128 == 0)
#pragma unroll
    for (int j = 0; j < 4; ++j) {
        const int n = n0 + wn + j * 16 + lrow;
        const float bb = job ? ((n < 256) ? b_off[n] : b_attn[n - 256]) : b_val[n];
#pragma unroll
        for (int i = 0; i < 4; ++i) {
            const int mrow = m0 + wm + i * 16 + kq * 4;
#pragma unroll
            for (int r = 0; r < 4; ++r) {
                const float v = acc[i][j][r] + bb;
                const unsigned short hv = (unsigned short)__half_as_ushort(__float2half(v));
                if (job) {
                    oa_h[(size_t)(mrow + r) * 384 + n] = hv;
                } else {
                    const int pix = (mrow + r) - b * LQ_;
                    const int h = n >> 5, c = n & 31;
                    val_h[((size_t)(b * NH + h) * LQ_ + pix) * HD + c] = hv;
                }
            }
        }
    }
}

// ---------------------------------------------------------------------------
// out = sampled(bf16) @ Wt_out + b_out -> f32. grid (2, 340) (x = n for LLC
// locality of the shared A-tile).
// ---------------------------------------------------------------------------
__global__ __launch_bounds__(256) void gemm_out(const unsigned short* __restrict__ Ab,
                                                const unsigned short* __restrict__ Bt,
                                                const float* __restrict__ bias,
                                                float* __restrict__ C) {
    __shared__ unsigned short As[128 * 32];
    __shared__ unsigned short Bs[128 * 32];
    const int t = threadIdx.x;
    const int wv = t >> 6;
    const int ln = t & 63;
    const int n0 = blockIdx.x * 128;
    const int m0 = blockIdx.y * 128;
    const int N = 256, K = 256;
    const int wm = (wv & 1) * 64;
    const int wn = (wv >> 1) * 64;
    const int lrow = ln & 15;
    const int kq = ln >> 4;

    f32x4 acc[4][4] = {};

    for (int k0 = 0; k0 < K; k0 += 32) {
#pragma unroll
        for (int c = 0; c < 2; ++c) {
            const int o = c * 4096 + t * 16;
            const int row = o >> 6;
            const int ke = (o & 63) >> 1;
            const unsigned short* ga = Ab + (size_t)(m0 + row) * K + k0 + ke;
            const unsigned short* gb = Bt + (size_t)(n0 + row) * K + k0 + ke;
            __builtin_amdgcn_global_load_lds(
                (const __attribute__((address_space(1))) void*)ga,
                (__attribute__((address_space(3))) void*)((char*)As + o), 16, 0, 0);
            __builtin_amdgcn_global_load_lds(
                (const __attribute__((address_space(1))) void*)gb,
                (__attribute__((address_space(3))) void*)((char*)Bs + o), 16, 0, 0);
        }
        __syncthreads();

        bf16x8 af[4], bfr[4];
#pragma unroll
        for (int i = 0; i < 4; ++i) {
            af[i]  = *(const bf16x8*)((char*)As + (wm + i * 16 + lrow) * 64 + kq * 16);
            bfr[i] = *(const bf16x8*)((char*)Bs + (wn + i * 16 + lrow) * 64 + kq * 16);
        }
#pragma unroll
        for (int i = 0; i < 4; ++i)
#pragma unroll
            for (int j = 0; j < 4; ++j)
                acc[i][j] = __builtin_amdgcn_mfma_f32_16x16x32_bf16(af[i], bfr[j], acc[i][j], 0, 0, 0);
        __syncthreads();
    }

#pragma unroll
    for (int j = 0; j < 4; ++j) {
        const int n = n0 + wn + j * 16 + lrow;
        const float bb = bias[n];
#pragma unroll
        for (int i = 0; i < 4; ++i) {
            const int mrow = m0 + wm + i * 16 + kq * 4;
#pragma unroll
            for (int r = 0; r < 4; ++r)
                C[(size_t)(mrow + r) * N + n] = acc[i][j][r] + bb;
        }
    }
}

// ---------------------------------------------------------------------------
// Deformable sampling v5: block = 4 queries x 4 waves; wave = 1 query
// (64 lanes = 8 heads x 8 dg). Value layout [b][h][pix][32] f16 makes the
// x-corner pair (x0,x0+1) a contiguous 128 B segment; 8 dg-lanes cover it.
// Per (l,p): 2 wave-gathers (row y0, row y1) instead of 4. shfl_xor(4)
// combines x0/x1 partials. LDS entry per sample: {idx0, idx1, w(l0,r0),
// w(l1,r1)} 16 B, bank-swizzled.
// ---------------------------------------------------------------------------
#define QB 4
__device__ __forceinline__ void accum4(const uint4& v, float w, float* acc) {
#pragma unroll
    for (int c = 0; c < 4; ++c) {
        const __half2 h = u2h2((&v.x)[c]);
        acc[c * 2]     = fmaf(w, __low2float(h),  acc[c * 2]);
        acc[c * 2 + 1] = fmaf(w, __high2float(h), acc[c * 2 + 1]);
    }
}

__global__ __launch_bounds__(256) void msda_sample5(const unsigned short* __restrict__ value,
                                                    const unsigned short* __restrict__ oa,
                                                    const float* __restrict__ refp,
                                                    unsigned short* __restrict__ samp) {
    __shared__ char smem[8320];
    unsigned int* s_pkw = (unsigned int*)smem;            // 8 KB (phase B), aliases below
    float* s_off   = (float*)smem;                        // 4 KB
    float* s_logit = (float*)(smem + 4096);               // 2 KB
    float* s_aw    = (float*)(smem + 6144);               // 2 KB
    float* s_ref   = (float*)(smem + 8192);               // 128 B (non-aliased)

    const int t = threadIdx.x;
    const int j = blockIdx.x;                  // 10880 blocks
    const int bq0 = ((j & 7) * 1360 + (j >> 3)) * QB;   // XCDs 0-3 -> b0, 4-7 -> b1
    const int b = bq0 / LQ_;

    // phase 0: stage oa (f16 -> f32) + refs, nontemporal
    {
        const unsigned short* oab = oa + (size_t)bq0 * 384;
        const int q = t >> 6, c = t & 63;
        u32x2 r0 = __builtin_nontemporal_load((const u32x2*)(oab + (size_t)q * 384) + c);
        float2 f0 = __half22float2(u2h2(r0.x));
        float2 f1 = __half22float2(u2h2(r0.y));
        f32x4 o0 = {f0.x, f0.y, f1.x, f1.y};
        ((f32x4*)s_off)[q * 64 + c] = o0;
        unsigned int r1 = __builtin_nontemporal_load((const unsigned int*)(oab + (size_t)q * 384 + 256) + c);
        float2 g0 = __half22float2(u2h2(r1));
        ((float2*)s_logit)[q * 64 + c] = make_float2(g0.x, g0.y);
        if (t < 8)
            ((f32x4*)s_ref)[t] = __builtin_nontemporal_load((const f32x4*)(refp + (size_t)bq0 * 8) + t);
    }
    __syncthreads();

    // phase A1: 32 softmaxes (q,h) over 16 logits
    if (t < 32) {
        const float* lg = s_logit + (t >> 3) * 128 + (t & 7) * 16;
        float m = -1e30f;
#pragma unroll
        for (int i = 0; i < 16; ++i) m = fmaxf(m, lg[i]);
        float e[16], s = 0.f;
#pragma unroll
        for (int i = 0; i < 16; ++i) { e[i] = __expf(lg[i] - m); s += e[i]; }
        const float inv = 1.f / s;
#pragma unroll
        for (int i = 0; i < 16; ++i) s_aw[t * 16 + i] = e[i] * inv;
    }
    __syncthreads();

    // phase A2: 2 samples/thread -> registers
    uint4 ent[2];
    int wrd[2];
    {
        const int Wls[4] = {128, 64, 32, 16};
        const int Hls[4] = {128, 64, 32, 16};
        const int st_[4] = {0, 16384, 20480, 21504};
#pragma unroll
        for (int ii = 0; ii < 2; ++ii) {
            const int s = t * 2 + ii;
            const int q = s >> 7;
            const int rest = s & 127;        // h*16 + lp
            const int h = rest >> 4;
            const int lp = rest & 15;
            const int l = lp >> 2;
            const int Wl = Wls[l], Hl = Hls[l], base = st_[l];
            const float ix = s_ref[q * 8 + l * 2]     * (float)Wl - 0.5f + s_off[q * 256 + rest * 2];
            const float iy = s_ref[q * 8 + l * 2 + 1] * (float)Hl - 0.5f + s_off[q * 256 + rest * 2 + 1];
            const float fix = floorf(ix), fiy = floorf(iy);
            const int x0 = (int)fix, y0 = (int)fiy;
            const float fx = ix - fix, fy = iy - fiy;
            // x-pair: start sx in [0, Wl-2]; (wl, wr) = weights of pixels sx, sx+1
            int sx; float wl, wr;
            if (x0 < 0)            { sx = 0;      wl = (x0 == -1) ? fx : 0.f;        wr = 0.f; }
            else if (x0 >= Wl - 1) { sx = Wl - 2; wl = 0.f; wr = (x0 == Wl - 1) ? (1.f - fx) : 0.f; }
            else                   { sx = x0;     wl = 1.f - fx;                     wr = fx; }
            // y rows
            const float g0 = ((y0 >= 0) & (y0 < Hl)) ? (1.f - fy) : 0.f;
            const float g1 = ((y0 + 1 >= 0) & (y0 + 1 < Hl)) ? fy : 0.f;
            const int cy0 = min(max(y0, 0), Hl - 1);
            const int cy1 = min(max(y0 + 1, 0), Hl - 1);
            const float aw = s_aw[(q * 8 + h) * 16 + lp];
            ent[ii].x = (unsigned int)(base + cy0 * Wl + sx);
            ent[ii].y = (unsigned int)(base + cy1 * Wl + sx);
            ent[ii].z = pk2h(aw * wl * g0, aw * wr * g0);
            ent[ii].w = pk2h(aw * wl * g1, aw * wr * g1);
            wrd[ii] = q * 512 + lp * 32 + (((h ^ (lp & 7))) << 2);
        }
    }
    __syncthreads();  // phase-A reads done; safe to overwrite aliased region

#pragma unroll
    for (int ii = 0; ii < 2; ++ii)
        *(uint4*)&s_pkw[wrd[ii]] = ent[ii];
    __syncthreads();

    // phase B: wave = query; lane = h*8 + dg; dg spans 128 B = pixels (sx, sx+1)
    const int q = t >> 6;
    const int lane = t & 63;
    const int h = lane >> 3;
    const int dg = lane & 7;
    const unsigned short* vb = value + ((size_t)(b * NH + h) * LQ_) * HD + dg * 8;

    float acc[8] = {0.f, 0.f, 0.f, 0.f, 0.f, 0.f, 0.f, 0.f};
#pragma unroll
    for (int lp = 0; lp < 16; ++lp) {
        const uint4 pk = *(const uint4*)&s_pkw[q * 512 + lp * 32 + ((h ^ (lp & 7)) << 2)];
        const uint4 v0 = *(const uint4*)(vb + (size_t)pk.x * HD);
        const uint4 v1 = *(const uint4*)(vb + (size_t)pk.y * HD);
        const __half2 w0 = u2h2(pk.z), w1 = u2h2(pk.w);
        const float f0 = (dg < 4) ? __low2float(w0) : __high2float(w0);
        const float f1 = (dg < 4) ? __low2float(w1) : __high2float(w1);
        accum4(v0, f0, acc);
        accum4(v1, f1, acc);
    }
    // combine x0 (dg<4) and x1 (dg>=4) partials: lanes dg and dg^4 hold same channels
#pragma unroll
    for (int i = 0; i < 8; ++i) acc[i] += __shfl_xor(acc[i], 4);

    if (dg < 4) {
        u32x4 o;
        o.x = pk2bf(acc[0], acc[1]);
        o.y = pk2bf(acc[2], acc[3]);
        o.z = pk2bf(acc[4], acc[5]);
        o.w = pk2bf(acc[6], acc[7]);
        __builtin_nontemporal_store(o, (u32x4*)(samp + (size_t)(bq0 + q) * 256 + h * HD + dg * 8));
    }
}

extern "C" void kernel_launch(void* const* d_in, const int* in_sizes, int n_in,
                              void* d_out, int out_size, void* d_ws, size_t ws_size,
                              hipStream_t stream) {
    const float* query  = (const float*)d_in[0];
    const float* refp   = (const float*)d_in[1];
    const float* inpf   = (const float*)d_in[2];
    const float* W_off  = (const float*)d_in[3];
    const float* b_off  = (const float*)d_in[4];
    const float* W_attn = (const float*)d_in[5];
    const float* b_attn = (const float*)d_in[6];
    const float* W_val  = (const float*)d_in[7];
    const float* b_val  = (const float*)d_in[8];
    const float* W_out  = (const float*)d_in[9];
    const float* b_out  = (const float*)d_in[10];
    float* out = (float*)d_out;

    char* ws = (char*)d_ws;
    unsigned short* val_h   = (unsigned short*)(ws + WS_VAL);
    unsigned short* samp_bf = (unsigned short*)(ws + WS_SAMP);
    unsigned short* oa_h    = (unsigned short*)(ws + WS_OA);
    unsigned short* wt      = (unsigned short*)(ws + WS_WT);
    unsigned short* Wt_val  = wt;
    unsigned short* Wt_oa   = wt + 65536;
    unsigned short* Wt_out  = wt + 163840;

    const int M = B_ * LQ_;          // 43520

    wt_cvt_all<<<dim3(16, 16, 4), 256, 0, stream>>>(W_val, W_off, W_attn, W_out, wt);

    // merged value + off/attn GEMMs
    gemm_pre<<<dim3(5, M / 128), 256, 0, stream>>>(
        inpf, query, Wt_val, Wt_oa, b_val, b_off, b_attn, val_h, oa_h);

    // sampling
    msda_sample5<<<dim3(M / QB), 256, 0, stream>>>(val_h, oa_h, refp, samp_bf);

    // output projection
    gemm_out<<<dim3(2, M / 128), 256, 0, stream>>>(samp_bf, Wt_out, b_out, out);
}